// Round 8
// baseline (361.797 us; speedup 1.0000x reference)
//
#include <hip/hip_runtime.h>

// Problem constants (fixed by the reference)
#define NN 32768      // nodes
#define EE 262144     // edges
#define DM 512        // input/model dim (K of the big GEMM)
#define NQKV 1536     // q|k|v concatenated
#define NHEAD 8
#define DHEAD 64

typedef unsigned short u16;
typedef unsigned int u32;
typedef __attribute__((ext_vector_type(8))) short bf16x8;   // MFMA A/B operand (8 bf16)
typedef __attribute__((ext_vector_type(4))) float f32x4;    // MFMA C/D
typedef __attribute__((ext_vector_type(8))) u16 u16x8;
typedef __attribute__((ext_vector_type(4))) u32 u32x4;

__device__ __forceinline__ float bf2f(u16 u) {
  union { u32 i; float f; } x; x.i = ((u32)u) << 16; return x.f;
}
__device__ __forceinline__ float bflo(u32 p) {
  union { u32 i; float f; } x; x.i = p << 16; return x.f;
}
__device__ __forceinline__ float bfhi(u32 p) {
  union { u32 i; float f; } x; x.i = p & 0xFFFF0000u; return x.f;
}
__device__ __forceinline__ u16 f2bf(float f) {
  union { float f; u32 i; } x; x.f = f;
  u32 r = x.i + 0x7FFFu + ((x.i >> 16) & 1u);   // RNE
  return (u16)(r >> 16);
}

__device__ __forceinline__ void load_lds16(const u16* g, u16* l) {
  __builtin_amdgcn_global_load_lds(
      (const __attribute__((address_space(1))) char*)(const void*)g,
      (__attribute__((address_space(3))) char*)(void*)l, 16, 0, 0);
}

// XOR chunk swizzle for the 4x16B chunks of a 32-elem LDS row.
__device__ __forceinline__ int swz(int r, int s) {
  return s ^ (r & 3) ^ ((r >> 2) & 1);
}

// ---------------------------------------------------------------------------
// prep_mega: ALL independent preprocessing in ONE launch (block-range zones).
// Zone order: wt & bias FIRST (deep-reduction, small block counts) so they
// start immediately and overlap with cast_h / count_deg.
//   [0, 192)         wt       : Wt[perm(j)][kk] = sum_m Win[kk][m]*Wsel[m][j]
//                               (fp32 tiles; replaces tcast_w+cast_win+gemm_wt;
//                               R6 transpose bug fixed: Bs holds Win[kk][m])
//   [192, 198)       bias     : bias[perm(j)] = (bin.Wsel[:,j]+bsel[j])*scale
//   [198, 1222)      count_deg: degree histogram of `row` (deg pre-zeroed by
//                               the memset dispatched before this kernel)
//   [1222, 9414)     cast_h   : h fp32 -> bf16 (GEMM A operand)
// Output column permutation: q_j -> j; k_d -> 512+2d; v_d -> 513+2d, so the
// QKV GEMM's columns ARE the unified row layout [q(512) | kv-interleaved].
// ---------------------------------------------------------------------------
#define GB_WT    192
#define GB_BIAS  6
#define GB_CNTD  1024
#define GB_CASTH 8192
__global__ __launch_bounds__(256) void prep_mega(
    const float* __restrict__ h, u16* __restrict__ hb,
    const float* __restrict__ Win,
    const float* __restrict__ Wq, const float* __restrict__ Wk,
    const float* __restrict__ Wv, u16* __restrict__ Wt,
    const float* __restrict__ bin, const float* __restrict__ bq,
    const float* __restrict__ bk, const float* __restrict__ bv,
    float* __restrict__ bias,
    const int* __restrict__ row, int* __restrict__ deg) {
  __shared__ float As[32][68];   // As[d][jo]  = Wsel[k0+d][jj0+jo]
  __shared__ float Bs[64][36];   // Bs[kko][d] = Win[kk0+kko][k0+d]
  const int tid = threadIdx.x;
  int b = blockIdx.x;

  if (b < GB_WT) {                          // ---- wt (fp32 tile GEMM) ----
    const int jt = b >> 3;                  // 0..23 : logical j-tile
    const int kt = b & 7;                   // 0..7  : kk-tile
    const int z = jt >> 3;                  // 0=q,1=k,2=v
    const float* W = (z == 0) ? Wq : (z == 1) ? Wk : Wv;
    const float scale = (z == 0) ? 0.125f : 1.0f;
    const int jj0 = (jt & 7) * 64;          // col block in Wsel (j)
    const int kk0 = kt * 64;                // row block in Win  (kk)
    const int tj = tid >> 4, tk = tid & 15;
    float acc[4][4] = {};
    for (int k0 = 0; k0 < 512; k0 += 32) {  // reduction dim m
#pragma unroll
      for (int i = 0; i < 8; ++i) {
        const int idx = tid + i * 256;      // 0..2047
        // As: 32 rows (m) x 64 cols (j), coalesced over jo
        const int ami = idx >> 6, ajo = idx & 63;
        As[ami][ajo] = W[(size_t)(k0 + ami) * 512 + jj0 + ajo];
        // Bs: 64 rows (kk) x 32 cols (m), coalesced over m
        const int bkk = idx >> 5, bmi = idx & 31;
        Bs[bkk][bmi] = Win[(size_t)(kk0 + bkk) * 512 + k0 + bmi];
      }
      __syncthreads();
#pragma unroll
      for (int mi = 0; mi < 32; ++mi) {
        float4 av = *(const float4*)&As[mi][tj * 4];
        const float* ap = (const float*)&av;
        float bv4[4] = { Bs[tk * 4 + 0][mi], Bs[tk * 4 + 1][mi],
                         Bs[tk * 4 + 2][mi], Bs[tk * 4 + 3][mi] };
#pragma unroll
        for (int a2 = 0; a2 < 4; ++a2)
#pragma unroll
          for (int b2 = 0; b2 < 4; ++b2)
            acc[a2][b2] = fmaf(ap[a2], bv4[b2], acc[a2][b2]);
      }
      __syncthreads();
    }
#pragma unroll
    for (int a2 = 0; a2 < 4; ++a2) {
      const int j = jt * 64 + tj * 4 + a2;  // logical output col 0..1535
      const int pr = (j < 512) ? j
                   : (j < 1024) ? (512 + 2 * (j - 512))
                                : (513 + 2 * (j - 1024));
#pragma unroll
      for (int b2 = 0; b2 < 4; ++b2)
        Wt[(size_t)pr * 512 + kk0 + tk * 4 + b2] = f2bf(acc[a2][b2] * scale);
    }
    return;
  }
  b -= GB_WT;
  if (b < GB_BIAS) {                        // ---- bias (no atomics) ----
    const int j = b * 256 + tid;            // logical index 0..1535
    const float* Wsel; const float* bsel; int jj; float scale = 1.0f; int pos;
    if (j < 512)       { Wsel = Wq; bsel = bq; jj = j;        scale = 0.125f; pos = j; }
    else if (j < 1024) { Wsel = Wk; bsel = bk; jj = j - 512;  pos = 512 + 2 * jj; }
    else               { Wsel = Wv; bsel = bv; jj = j - 1024; pos = 513 + 2 * jj; }
    float s0 = 0.f, s1 = 0.f, s2 = 0.f, s3 = 0.f;
    for (int m = 0; m < 512; m += 4) {
      s0 = fmaf(bin[m],     Wsel[(size_t)m * 512 + jj],       s0);
      s1 = fmaf(bin[m + 1], Wsel[(size_t)(m + 1) * 512 + jj], s1);
      s2 = fmaf(bin[m + 2], Wsel[(size_t)(m + 2) * 512 + jj], s2);
      s3 = fmaf(bin[m + 3], Wsel[(size_t)(m + 3) * 512 + jj], s3);
    }
    bias[pos] = (((s0 + s1) + (s2 + s3)) + bsel[jj]) * scale;
    return;
  }
  b -= GB_BIAS;
  if (b < GB_CNTD) {                        // ---- count_deg ----
    const int e = b * 256 + tid;
    atomicAdd(&deg[row[e]], 1);
    return;
  }
  b -= GB_CNTD;
  {                                         // ---- cast_h ----
    const int i = (b * 256 + tid) * 8;
    float4 a = *(const float4*)&h[i];
    float4 c = *(const float4*)&h[i + 4];
    u16x8 o = { f2bf(a.x), f2bf(a.y), f2bf(a.z), f2bf(a.w),
                f2bf(c.x), f2bf(c.y), f2bf(c.z), f2bf(c.w) };
    *(u16x8*)&hb[i] = o;
  }
}

// ---------------------------------------------------------------------------
// CSR build: scan + fill (R3/R5-proven forms; counting folded into prep_mega)
// ---------------------------------------------------------------------------
__global__ void scan_deg(const int* __restrict__ deg, int* __restrict__ row_ptr,
                         int* __restrict__ cursor) {
  __shared__ int sums[1024];
  const int t = threadIdx.x;
  const int base = t * 32;
  int loc[32];
  int s = 0;
#pragma unroll
  for (int i = 0; i < 32; ++i) { loc[i] = s; s += deg[base + i]; }
  sums[t] = s;
  __syncthreads();
  for (int off = 1; off < 1024; off <<= 1) {
    int v = (t >= off) ? sums[t - off] : 0;
    __syncthreads();
    sums[t] += v;
    __syncthreads();
  }
  const int excl = sums[t] - s;
#pragma unroll
  for (int i = 0; i < 32; ++i) {
    const int val = excl + loc[i];
    row_ptr[base + i] = val;
    cursor[base + i] = val;
  }
  if (t == 1023) row_ptr[NN] = sums[1023];
}

__global__ void fill_csr(const int* __restrict__ row, const int* __restrict__ col,
                         int* __restrict__ cursor, int* __restrict__ dst) {
  const int e = blockIdx.x * 256 + threadIdx.x;
  const int r = row[e];
  const int p = atomicAdd(&cursor[r], 1);
  dst[p] = col[e];
}

// ---------------------------------------------------------------------------
// QKV = h_bf16 @ Wt^T + bias   (M=32768, N=1536, K=512)
// 128^2 tile + XCD-aware bijective swizzle + ring-3 LDS (48 KiB, 3 blocks/CU)
// with COUNTED vmcnt + lgkmcnt(0) at the barrier (R4 race fix). Verbatim
// from the round-5 passing build (structure ceiling; leave alone).
// ---------------------------------------------------------------------------
__global__ __launch_bounds__(256, 2) void gemm_qkv(
    const u16* __restrict__ A,    // [32768,512] bf16, row-major
    const u16* __restrict__ B,    // [1536,512] bf16, N-major, rows permuted
    const float* __restrict__ bias,  // permuted to match columns
    u16* __restrict__ C) {        // qkv [32768,1536] bf16 unified
  __shared__ u16 As[3][128 * 32];
  __shared__ u16 Bs[3][128 * 32];
  const int tid = threadIdx.x;
  const int lane = tid & 63;
  const int wave = tid >> 6;
  const int quad = lane >> 4;
  const int l16 = lane & 15;

  const int bid = blockIdx.y * 12 + blockIdx.x;
  const int sw = (bid & 7) * 384 + (bid >> 3);
  const int bx = sw % 12;
  const int by = sw / 12;
  const int m0 = by * 128;
  const int n0 = bx * 128;
  const int wm = (wave >> 1) * 64;
  const int wn = (wave & 1) * 64;

  const int c0 = tid, c1 = tid + 256;
  const int r0 = c0 >> 2, ko0 = swz(r0, c0 & 3) * 8;
  const int r1 = c1 >> 2, ko1 = swz(r1, c1 & 3) * 8;
  const u16* Ag0 = A + (size_t)(m0 + r0) * DM + ko0;
  const u16* Ag1 = A + (size_t)(m0 + r1) * DM + ko1;
  const u16* Bg0 = B + (size_t)(n0 + r0) * DM + ko0;
  const u16* Bg1 = B + (size_t)(n0 + r1) * DM + ko1;

  f32x4 acc[4][4];
#pragma unroll
  for (int i = 0; i < 4; ++i)
#pragma unroll
    for (int j = 0; j < 4; ++j) acc[i][j] = (f32x4){0.f, 0.f, 0.f, 0.f};

  // prologue: stage tiles 0,1 (4 loads per tile per thread)
  load_lds16(Ag0, &As[0][c0 * 8]);
  load_lds16(Bg0, &Bs[0][c0 * 8]);
  load_lds16(Ag1, &As[0][c1 * 8]);
  load_lds16(Bg1, &Bs[0][c1 * 8]);
  load_lds16(Ag0 + 32, &As[1][c0 * 8]);
  load_lds16(Bg0 + 32, &Bs[1][c0 * 8]);
  load_lds16(Ag1 + 32, &As[1][c1 * 8]);
  load_lds16(Bg1 + 32, &Bs[1][c1 * 8]);

#pragma unroll
  for (int t = 0; t < 16; ++t) {
    const int bt = t % 3;
    // counted wait: tile t landed (oldest 4), tile t+1 stays in flight;
    // lgkmcnt(0) = this wave's prior ds_reads done -> overwrite-safe.
    if (t < 15) asm volatile("s_waitcnt vmcnt(4) lgkmcnt(0)\n\ts_barrier" ::: "memory");
    else        asm volatile("s_waitcnt vmcnt(0) lgkmcnt(0)\n\ts_barrier" ::: "memory");
    // stage t+2 into buf[(t+2)%3] = buf[(t-1)%3]; all reads of tile t-1
    // completed before the barrier above (lgkmcnt(0) drained them).
    if (t < 14) {
      const int b2 = (t + 2) % 3;
      const int kg = (t + 2) * 32;
      load_lds16(Ag0 + kg, &As[b2][c0 * 8]);
      load_lds16(Bg0 + kg, &Bs[b2][c0 * 8]);
      load_lds16(Ag1 + kg, &As[b2][c1 * 8]);
      load_lds16(Bg1 + kg, &Bs[b2][c1 * 8]);
    }
    bf16x8 a[4], b[4];
#pragma unroll
    for (int i = 0; i < 4; ++i) {
      const int ra = wm + i * 16 + l16;
      const int rb = wn + i * 16 + l16;
      a[i] = *(const bf16x8*)&As[bt][ra * 32 + swz(ra, quad) * 8];
      b[i] = *(const bf16x8*)&Bs[bt][rb * 32 + swz(rb, quad) * 8];
    }
#pragma unroll
    for (int mi = 0; mi < 4; ++mi)
#pragma unroll
      for (int ni = 0; ni < 4; ++ni)
        acc[mi][ni] = __builtin_amdgcn_mfma_f32_16x16x32_bf16(a[mi], b[ni], acc[mi][ni], 0, 0, 0);
  }

  // epilogue: C/D layout col=lane&15, row=quad*4+r (verified m89/m91)
#pragma unroll
  for (int ni = 0; ni < 4; ++ni) {
    const int coln = n0 + wn + ni * 16 + l16;
    const float bv = bias[coln];
#pragma unroll
    for (int mi = 0; mi < 4; ++mi) {
#pragma unroll
      for (int r = 0; r < 4; ++r) {
        const int rowm = m0 + wm + mi * 16 + quad * 4 + r;
        C[(size_t)rowm * NQKV + coln] = f2bf(acc[mi][ni][r] + bv);
      }
    }
  }
}

// ---------------------------------------------------------------------------
// Fused sparse attention: ONE WAVE PER NODE; lane l owns dims l*8..l*8+7.
// Round-1 proven form (CHUNK=4 clamped, VGPR 48): fastest of the three
// measured structural variants (88-91 us, FETCH pinned 267 MB -> gather-bound).
// ---------------------------------------------------------------------------
__global__ __launch_bounds__(256) void attn_agg(
    const u16* __restrict__ qkv16, const u32* __restrict__ qkv32,
    const int* __restrict__ row_ptr, const int* __restrict__ dst,
    float* __restrict__ out) {
  const int gt = blockIdx.x * 256 + threadIdx.x;
  const int node = gt >> 6;
  const int lane = gt & 63;
  const u16x8 qr = *(const u16x8*)&qkv16[(size_t)node * NQKV + lane * 8];
  float qf[8];
#pragma unroll
  for (int j = 0; j < 8; ++j) qf[j] = bf2f(qr[j]);

  const int beg = row_ptr[node];
  const int end = row_ptr[node + 1];
  float acc[8] = {0.f,0.f,0.f,0.f,0.f,0.f,0.f,0.f};
  float denom = 0.f;

  for (int e = beg; e < end; e += 4) {
    u32 p[4][8];
    int idx[4];
#pragma unroll
    for (int jj = 0; jj < 4; ++jj) {
      const int ee = min(e + jj, end - 1);
      idx[jj] = dst[ee];
    }
#pragma unroll
    for (int jj = 0; jj < 4; ++jj) {
      const u32* pp = qkv32 + (size_t)idx[jj] * 768 + 256 + lane * 8;
      *(u32x4*)&p[jj][0] = *(const u32x4*)pp;        // dwordx4
      *(u32x4*)&p[jj][4] = *(const u32x4*)(pp + 4);  // dwordx4
    }
#pragma unroll
    for (int jj = 0; jj < 4; ++jj) {
      float s = 0.f;
#pragma unroll
      for (int j = 0; j < 8; ++j) s = fmaf(qf[j], bflo(p[jj][j]), s);
      s += __shfl_xor(s, 1, 64);   // reduce within the 8-lane head group
      s += __shfl_xor(s, 2, 64);
      s += __shfl_xor(s, 4, 64);
      const float ex = (e + jj < end) ? __expf(s) : 0.f;
      denom += ex;
#pragma unroll
      for (int j = 0; j < 8; ++j) acc[j] = fmaf(ex, bfhi(p[jj][j]), acc[j]);
    }
  }

  const float inv = (end > beg) ? (1.0f / denom) : 0.f;   // deg-0 rows -> 0
  float4 o0 = { acc[0] * inv, acc[1] * inv, acc[2] * inv, acc[3] * inv };
  float4 o1 = { acc[4] * inv, acc[5] * inv, acc[6] * inv, acc[7] * inv };
  float* op = &out[(size_t)node * 512 + lane * 8];
  *(float4*)op = o0;
  *(float4*)(op + 4) = o1;
}

// ---------------------------------------------------------------------------
extern "C" void kernel_launch(void* const* d_in, const int* in_sizes, int n_in,
                              void* d_out, int out_size, void* d_ws, size_t ws_size,
                              hipStream_t stream) {
  const float* h   = (const float*)d_in[0];
  const int*   row = (const int*)d_in[1];
  const int*   col = (const int*)d_in[2];
  const float* Win = (const float*)d_in[3];
  const float* bin = (const float*)d_in[4];
  const float* Wq  = (const float*)d_in[5];
  const float* bq  = (const float*)d_in[6];
  const float* Wk  = (const float*)d_in[7];
  const float* bk  = (const float*)d_in[8];
  const float* Wv  = (const float*)d_in[9];
  const float* bv  = (const float*)d_in[10];
  float* out = (float*)d_out;

  char* ws = (char*)d_ws;
  u16*   qkv     = (u16*)(ws + 0);           // 32768*1536*2 = 100,663,296
  u16*   hb      = (u16*)(ws + 100663296);   // 32768*512*2  =  33,554,432
  u16*   Wt      = (u16*)(ws + 134217728);   // 1536*512*2   =   1,572,864
  float* bias    = (float*)(ws + 135790592); // 1536*4
  int*   deg     = (int*)(ws + 135796736);   // 32768*4
  int*   row_ptr = (int*)(ws + 135927808);   // 32769*4 (+pad)
  int*   cursor  = (int*)(ws + 136058888);   // 32768*4
  int*   dst     = (int*)(ws + 136189960);   // 262144*4

  // 6 dispatches (was 8 in the R5 passing build): gemm_wt fused into
  // prep_mega's wt zone; bias memset eliminated (non-atomic bias zone).
  (void)hipMemsetAsync(deg, 0, NN * sizeof(int), stream);
  hipLaunchKernelGGL(prep_mega,
                     dim3(GB_WT + GB_BIAS + GB_CNTD + GB_CASTH), dim3(256), 0, stream,
                     h, hb, Win, Wq, Wk, Wv, Wt, bin, bq, bk, bv, bias, row, deg);
  hipLaunchKernelGGL(scan_deg,  dim3(1), dim3(1024), 0, stream, deg, row_ptr, cursor);
  hipLaunchKernelGGL(fill_csr,  dim3(EE / 256), dim3(256), 0, stream, row, col, cursor, dst);
  hipLaunchKernelGGL(gemm_qkv,  dim3(NQKV / 128, NN / 128), dim3(256), 0, stream, hb, Wt, bias, qkv);
  hipLaunchKernelGGL(attn_agg,  dim3((NN * 64) / 256), dim3(256), 0, stream,
                     qkv, (const u32*)qkv, row_ptr, dst, out);
}

// Round 9
// 344.289 us; speedup vs baseline: 1.0509x; 1.0509x over previous
//
#include <hip/hip_runtime.h>

// Problem constants (fixed by the reference)
#define NN 32768      // nodes
#define EE 262144     // edges
#define DM 512        // input/model dim (K of the big GEMM)
#define NQKV 1536     // q|k|v concatenated
#define NHEAD 8
#define DHEAD 64

typedef unsigned short u16;
typedef unsigned int u32;
typedef __attribute__((ext_vector_type(8))) short bf16x8;   // MFMA A/B operand (8 bf16)
typedef __attribute__((ext_vector_type(4))) float f32x4;    // MFMA C/D
typedef __attribute__((ext_vector_type(8))) u16 u16x8;
typedef __attribute__((ext_vector_type(4))) u32 u32x4;

__device__ __forceinline__ float bf2f(u16 u) {
  union { u32 i; float f; } x; x.i = ((u32)u) << 16; return x.f;
}
__device__ __forceinline__ float bflo(u32 p) {
  union { u32 i; float f; } x; x.i = p << 16; return x.f;
}
__device__ __forceinline__ float bfhi(u32 p) {
  union { u32 i; float f; } x; x.i = p & 0xFFFF0000u; return x.f;
}
__device__ __forceinline__ u16 f2bf(float f) {
  union { float f; u32 i; } x; x.f = f;
  u32 r = x.i + 0x7FFFu + ((x.i >> 16) & 1u);   // RNE
  return (u16)(r >> 16);
}

__device__ __forceinline__ void load_lds16(const u16* g, u16* l) {
  __builtin_amdgcn_global_load_lds(
      (const __attribute__((address_space(1))) char*)(const void*)g,
      (__attribute__((address_space(3))) char*)(void*)l, 16, 0, 0);
}

// XOR chunk swizzle for the 4x16B chunks of a 32-elem LDS row.
__device__ __forceinline__ int swz(int r, int s) {
  return s ^ (r & 3) ^ ((r >> 2) & 1);
}

// ---------------------------------------------------------------------------
// prep_all: independent preprocessing, ONE launch, uniform-short zones only
// (R8 lesson: the deep fp32 wt-GEMM zone coupled into prep's tail, +23 us;
// Wt composition goes back to the dedicated MFMA kernel below).
//   [0, 6)        bias     : bias[perm(j)] = (bin.Wsel[:,j]+bsel[j])*scale
//   [6, 198)      tcast_w  : transpose-cast Wq/Wk/Wv -> At (permuted rows)
//   [198, 326)    cast_win : Win fp32 -> bf16 (B^T layout)
//   [326, 1350)   count_deg: degree histogram (deg pre-zeroed by memset)
//   [1350, 9542)  cast_h   : h fp32 -> bf16
// Output column permutation: q_j -> j; k_d -> 512+2d; v_d -> 513+2d.
// ---------------------------------------------------------------------------
#define GB_BIAS  6
#define GB_TCW   192
#define GB_CASTW 128
#define GB_CNTD  1024
#define GB_CASTH 8192
__global__ __launch_bounds__(256) void prep_all(
    const float* __restrict__ h, u16* __restrict__ hb,
    const float* __restrict__ Win, u16* __restrict__ Winb,
    const int* __restrict__ row, int* __restrict__ deg,
    const float* __restrict__ Wq, const float* __restrict__ Wk,
    const float* __restrict__ Wv, u16* __restrict__ At,
    const float* __restrict__ bin, const float* __restrict__ bq,
    const float* __restrict__ bk, const float* __restrict__ bv,
    float* __restrict__ bias) {
  __shared__ float t[64][65];
  const int tid = threadIdx.x;
  int b = blockIdx.x;

  if (b < GB_BIAS) {                        // ---- bias (no atomics) ----
    const int j = b * 256 + tid;            // logical index 0..1535
    const float* Wsel; const float* bsel; int jj; float scale = 1.0f; int pos;
    if (j < 512)       { Wsel = Wq; bsel = bq; jj = j;        scale = 0.125f; pos = j; }
    else if (j < 1024) { Wsel = Wk; bsel = bk; jj = j - 512;  pos = 512 + 2 * jj; }
    else               { Wsel = Wv; bsel = bv; jj = j - 1024; pos = 513 + 2 * jj; }
    float s0 = 0.f, s1 = 0.f, s2 = 0.f, s3 = 0.f;
    for (int m = 0; m < 512; m += 4) {
      s0 = fmaf(bin[m],     Wsel[(size_t)m * 512 + jj],       s0);
      s1 = fmaf(bin[m + 1], Wsel[(size_t)(m + 1) * 512 + jj], s1);
      s2 = fmaf(bin[m + 2], Wsel[(size_t)(m + 2) * 512 + jj], s2);
      s3 = fmaf(bin[m + 3], Wsel[(size_t)(m + 3) * 512 + jj], s3);
    }
    bias[pos] = (((s0 + s1) + (s2 + s3)) + bsel[jj]) * scale;
    return;
  }
  b -= GB_BIAS;
  if (b < GB_TCW) {                         // ---- tcast_w ----
    const int z = b / 64;                   // 0=q,1=k,2=v
    const int r64 = b % 64;
    const float* W = (z == 0) ? Wq : (z == 1) ? Wk : Wv;
    const float scale = (z == 0) ? 0.125f : 1.0f;
    const int m0 = (r64 >> 3) * 64;
    const int j0 = (r64 & 7) * 64;
    const int tx = tid & 63, ty = tid >> 6;
#pragma unroll
    for (int i = 0; i < 16; ++i) {
      const int r = ty * 16 + i;
      t[r][tx] = W[(size_t)(m0 + r) * 512 + (j0 + tx)];   // coalesced over tx
    }
    __syncthreads();
#pragma unroll
    for (int i = 0; i < 16; ++i) {
      const int j = j0 + ty * 16 + i;
      const int pr = (z == 0) ? j : (512 + 2 * j + (z - 1));  // permuted row
      At[(size_t)pr * 512 + (m0 + tx)] = f2bf(t[tx][ty * 16 + i] * scale);
    }
    return;
  }
  b -= GB_TCW;
  if (b < GB_CASTW) {                       // ---- cast_win ----
    const int i = (b * 256 + tid) * 8;
    float4 a = *(const float4*)&Win[i];
    float4 c = *(const float4*)&Win[i + 4];
    u16x8 o = { f2bf(a.x), f2bf(a.y), f2bf(a.z), f2bf(a.w),
                f2bf(c.x), f2bf(c.y), f2bf(c.z), f2bf(c.w) };
    *(u16x8*)&Winb[i] = o;
    return;
  }
  b -= GB_CASTW;
  if (b < GB_CNTD) {                        // ---- count_deg ----
    const int e = b * 256 + tid;
    atomicAdd(&deg[row[e]], 1);
    return;
  }
  b -= GB_CNTD;
  {                                         // ---- cast_h ----
    const int i = (b * 256 + tid) * 8;
    float4 a = *(const float4*)&h[i];
    float4 c = *(const float4*)&h[i + 4];
    u16x8 o = { f2bf(a.x), f2bf(a.y), f2bf(a.z), f2bf(a.w),
                f2bf(c.x), f2bf(c.y), f2bf(c.z), f2bf(c.w) };
    *(u16x8*)&hb[i] = o;
  }
}

// ---------------------------------------------------------------------------
// scan_deg: exclusive prefix over degrees (R3/R5-proven form)
// ---------------------------------------------------------------------------
__global__ void scan_deg(const int* __restrict__ deg, int* __restrict__ row_ptr,
                         int* __restrict__ cursor) {
  __shared__ int sums[1024];
  const int t = threadIdx.x;
  const int base = t * 32;
  int loc[32];
  int s = 0;
#pragma unroll
  for (int i = 0; i < 32; ++i) { loc[i] = s; s += deg[base + i]; }
  sums[t] = s;
  __syncthreads();
  for (int off = 1; off < 1024; off <<= 1) {
    int v = (t >= off) ? sums[t - off] : 0;
    __syncthreads();
    sums[t] += v;
    __syncthreads();
  }
  const int excl = sums[t] - s;
#pragma unroll
  for (int i = 0; i < 32; ++i) {
    const int val = excl + loc[i];
    row_ptr[base + i] = val;
    cursor[base + i] = val;
  }
  if (t == 1023) row_ptr[NN] = sums[1023];
}

// ---------------------------------------------------------------------------
// wt_fill: gemm_wt (48 MFMA blocks) + fill_csr (1024 blocks) merged — the two
// are mutually independent (wt needs prep's At/Winb; fill needs scan's
// cursor), so they overlap instead of serializing across a launch boundary.
//   [0, 48)      gemm_wt: Wt[j][kk] = sum_m At[j][m]*Winb[kk][m]
//                (M=1536, N=512, K=512; 128^2 + 2-phase, R5-proven form)
//   [48, 1072)   fill_csr
// ---------------------------------------------------------------------------
__global__ __launch_bounds__(256, 2) void wt_fill(
    const u16* __restrict__ A,    // At [1536][512] bf16 (rows pre-permuted)
    const u16* __restrict__ B,    // Winb [512][512] bf16 (B^T layout)
    u16* __restrict__ C,          // Wt [1536][512] bf16
    const int* __restrict__ row, const int* __restrict__ col,
    int* __restrict__ cursor, int* __restrict__ dst) {
  __shared__ u16 As[2][128 * 32];
  __shared__ u16 Bs[2][128 * 32];
  const int tid = threadIdx.x;

  if (blockIdx.x >= 48) {                   // ---- fill_csr ----
    const int e = (blockIdx.x - 48) * 256 + tid;
    const int r = row[e];
    const int p = atomicAdd(&cursor[r], 1);
    dst[p] = col[e];
    return;
  }

  // ---- gemm_wt ----
  const int lane = tid & 63;
  const int wave = tid >> 6;
  const int quad = lane >> 4;
  const int l16 = lane & 15;
  const int m0 = (blockIdx.x >> 2) * 128;   // 12 M-tiles
  const int n0 = (blockIdx.x & 3) * 128;    // 4 N-tiles
  const int wm = (wave >> 1) * 64;
  const int wn = (wave & 1) * 64;

  const int c0 = tid, c1 = tid + 256;
  const int r0 = c0 >> 2, ko0 = swz(r0, c0 & 3) * 8;
  const int r1 = c1 >> 2, ko1 = swz(r1, c1 & 3) * 8;
  const u16* Ag0 = A + (size_t)(m0 + r0) * DM + ko0;
  const u16* Ag1 = A + (size_t)(m0 + r1) * DM + ko1;
  const u16* Bg0 = B + (size_t)(n0 + r0) * DM + ko0;
  const u16* Bg1 = B + (size_t)(n0 + r1) * DM + ko1;

  f32x4 acc[4][4];
#pragma unroll
  for (int i = 0; i < 4; ++i)
#pragma unroll
    for (int j = 0; j < 4; ++j) acc[i][j] = (f32x4){0.f, 0.f, 0.f, 0.f};

  load_lds16(Ag0, &As[0][c0 * 8]);
  load_lds16(Bg0, &Bs[0][c0 * 8]);
  load_lds16(Ag1, &As[0][c1 * 8]);
  load_lds16(Bg1, &Bs[0][c1 * 8]);
  __syncthreads();

  int cur = 0;
#pragma unroll
  for (int kt = 32; kt < DM; kt += 32) {
    load_lds16(Ag0 + kt, &As[cur ^ 1][c0 * 8]);
    load_lds16(Bg0 + kt, &Bs[cur ^ 1][c0 * 8]);
    load_lds16(Ag1 + kt, &As[cur ^ 1][c1 * 8]);
    load_lds16(Bg1 + kt, &Bs[cur ^ 1][c1 * 8]);
    bf16x8 a[4], b[4];
#pragma unroll
    for (int i = 0; i < 4; ++i) {
      const int ra = wm + i * 16 + l16;
      const int rb = wn + i * 16 + l16;
      a[i] = *(const bf16x8*)&As[cur][ra * 32 + swz(ra, quad) * 8];
      b[i] = *(const bf16x8*)&Bs[cur][rb * 32 + swz(rb, quad) * 8];
    }
#pragma unroll
    for (int mi = 0; mi < 4; ++mi)
#pragma unroll
      for (int ni = 0; ni < 4; ++ni)
        acc[mi][ni] = __builtin_amdgcn_mfma_f32_16x16x32_bf16(a[mi], b[ni], acc[mi][ni], 0, 0, 0);
    __syncthreads();
    cur ^= 1;
  }
  {
    bf16x8 a[4], b[4];
#pragma unroll
    for (int i = 0; i < 4; ++i) {
      const int ra = wm + i * 16 + l16;
      const int rb = wn + i * 16 + l16;
      a[i] = *(const bf16x8*)&As[cur][ra * 32 + swz(ra, quad) * 8];
      b[i] = *(const bf16x8*)&Bs[cur][rb * 32 + swz(rb, quad) * 8];
    }
#pragma unroll
    for (int mi = 0; mi < 4; ++mi)
#pragma unroll
      for (int ni = 0; ni < 4; ++ni)
        acc[mi][ni] = __builtin_amdgcn_mfma_f32_16x16x32_bf16(a[mi], b[ni], acc[mi][ni], 0, 0, 0);
  }

#pragma unroll
  for (int ni = 0; ni < 4; ++ni) {
    const int coln = n0 + wn + ni * 16 + l16;
#pragma unroll
    for (int mi = 0; mi < 4; ++mi) {
#pragma unroll
      for (int r = 0; r < 4; ++r) {
        const int rowm = m0 + wm + mi * 16 + quad * 4 + r;
        C[(size_t)rowm * 512 + coln] = f2bf(acc[mi][ni][r]);
      }
    }
  }
}

// ---------------------------------------------------------------------------
// QKV = h_bf16 @ Wt^T + bias   (M=32768, N=1536, K=512)
// 128^2 tile + XCD-aware bijective swizzle + ring-3 LDS (48 KiB, 3 blocks/CU)
// with COUNTED vmcnt + lgkmcnt(0) at the barrier (R4 race fix). Verbatim
// from the round-5 passing build (structure ceiling; leave alone).
// ---------------------------------------------------------------------------
__global__ __launch_bounds__(256, 2) void gemm_qkv(
    const u16* __restrict__ A,    // [32768,512] bf16, row-major
    const u16* __restrict__ B,    // [1536,512] bf16, N-major, rows permuted
    const float* __restrict__ bias,  // permuted to match columns
    u16* __restrict__ C) {        // qkv [32768,1536] bf16 unified
  __shared__ u16 As[3][128 * 32];
  __shared__ u16 Bs[3][128 * 32];
  const int tid = threadIdx.x;
  const int lane = tid & 63;
  const int wave = tid >> 6;
  const int quad = lane >> 4;
  const int l16 = lane & 15;

  const int bid = blockIdx.y * 12 + blockIdx.x;
  const int sw = (bid & 7) * 384 + (bid >> 3);
  const int bx = sw % 12;
  const int by = sw / 12;
  const int m0 = by * 128;
  const int n0 = bx * 128;
  const int wm = (wave >> 1) * 64;
  const int wn = (wave & 1) * 64;

  const int c0 = tid, c1 = tid + 256;
  const int r0 = c0 >> 2, ko0 = swz(r0, c0 & 3) * 8;
  const int r1 = c1 >> 2, ko1 = swz(r1, c1 & 3) * 8;
  const u16* Ag0 = A + (size_t)(m0 + r0) * DM + ko0;
  const u16* Ag1 = A + (size_t)(m0 + r1) * DM + ko1;
  const u16* Bg0 = B + (size_t)(n0 + r0) * DM + ko0;
  const u16* Bg1 = B + (size_t)(n0 + r1) * DM + ko1;

  f32x4 acc[4][4];
#pragma unroll
  for (int i = 0; i < 4; ++i)
#pragma unroll
    for (int j = 0; j < 4; ++j) acc[i][j] = (f32x4){0.f, 0.f, 0.f, 0.f};

  // prologue: stage tiles 0,1 (4 loads per tile per thread)
  load_lds16(Ag0, &As[0][c0 * 8]);
  load_lds16(Bg0, &Bs[0][c0 * 8]);
  load_lds16(Ag1, &As[0][c1 * 8]);
  load_lds16(Bg1, &Bs[0][c1 * 8]);
  load_lds16(Ag0 + 32, &As[1][c0 * 8]);
  load_lds16(Bg0 + 32, &Bs[1][c0 * 8]);
  load_lds16(Ag1 + 32, &As[1][c1 * 8]);
  load_lds16(Bg1 + 32, &Bs[1][c1 * 8]);

#pragma unroll
  for (int t = 0; t < 16; ++t) {
    const int bt = t % 3;
    // counted wait: tile t landed (oldest 4), tile t+1 stays in flight;
    // lgkmcnt(0) = this wave's prior ds_reads done -> overwrite-safe.
    if (t < 15) asm volatile("s_waitcnt vmcnt(4) lgkmcnt(0)\n\ts_barrier" ::: "memory");
    else        asm volatile("s_waitcnt vmcnt(0) lgkmcnt(0)\n\ts_barrier" ::: "memory");
    // stage t+2 into buf[(t+2)%3] = buf[(t-1)%3]; all reads of tile t-1
    // completed before the barrier above (lgkmcnt(0) drained them).
    if (t < 14) {
      const int b2 = (t + 2) % 3;
      const int kg = (t + 2) * 32;
      load_lds16(Ag0 + kg, &As[b2][c0 * 8]);
      load_lds16(Bg0 + kg, &Bs[b2][c0 * 8]);
      load_lds16(Ag1 + kg, &As[b2][c1 * 8]);
      load_lds16(Bg1 + kg, &Bs[b2][c1 * 8]);
    }
    bf16x8 a[4], b[4];
#pragma unroll
    for (int i = 0; i < 4; ++i) {
      const int ra = wm + i * 16 + l16;
      const int rb = wn + i * 16 + l16;
      a[i] = *(const bf16x8*)&As[bt][ra * 32 + swz(ra, quad) * 8];
      b[i] = *(const bf16x8*)&Bs[bt][rb * 32 + swz(rb, quad) * 8];
    }
#pragma unroll
    for (int mi = 0; mi < 4; ++mi)
#pragma unroll
      for (int ni = 0; ni < 4; ++ni)
        acc[mi][ni] = __builtin_amdgcn_mfma_f32_16x16x32_bf16(a[mi], b[ni], acc[mi][ni], 0, 0, 0);
  }

  // epilogue: C/D layout col=lane&15, row=quad*4+r (verified m89/m91)
#pragma unroll
  for (int ni = 0; ni < 4; ++ni) {
    const int coln = n0 + wn + ni * 16 + l16;
    const float bv = bias[coln];
#pragma unroll
    for (int mi = 0; mi < 4; ++mi) {
#pragma unroll
      for (int r = 0; r < 4; ++r) {
        const int rowm = m0 + wm + mi * 16 + quad * 4 + r;
        C[(size_t)rowm * NQKV + coln] = f2bf(acc[mi][ni][r] + bv);
      }
    }
  }
}

// ---------------------------------------------------------------------------
// Fused sparse attention: ONE WAVE PER NODE; lane l owns dims l*8..l*8+7.
// Round-1 proven form (CHUNK=4 clamped, VGPR 48): fastest of the three
// measured structural variants (88-91 us, FETCH pinned 267 MB -> gather-bound).
// ---------------------------------------------------------------------------
__global__ __launch_bounds__(256) void attn_agg(
    const u16* __restrict__ qkv16, const u32* __restrict__ qkv32,
    const int* __restrict__ row_ptr, const int* __restrict__ dst,
    float* __restrict__ out) {
  const int gt = blockIdx.x * 256 + threadIdx.x;
  const int node = gt >> 6;
  const int lane = gt & 63;
  const u16x8 qr = *(const u16x8*)&qkv16[(size_t)node * NQKV + lane * 8];
  float qf[8];
#pragma unroll
  for (int j = 0; j < 8; ++j) qf[j] = bf2f(qr[j]);

  const int beg = row_ptr[node];
  const int end = row_ptr[node + 1];
  float acc[8] = {0.f,0.f,0.f,0.f,0.f,0.f,0.f,0.f};
  float denom = 0.f;

  for (int e = beg; e < end; e += 4) {
    u32 p[4][8];
    int idx[4];
#pragma unroll
    for (int jj = 0; jj < 4; ++jj) {
      const int ee = min(e + jj, end - 1);
      idx[jj] = dst[ee];
    }
#pragma unroll
    for (int jj = 0; jj < 4; ++jj) {
      const u32* pp = qkv32 + (size_t)idx[jj] * 768 + 256 + lane * 8;
      *(u32x4*)&p[jj][0] = *(const u32x4*)pp;        // dwordx4
      *(u32x4*)&p[jj][4] = *(const u32x4*)(pp + 4);  // dwordx4
    }
#pragma unroll
    for (int jj = 0; jj < 4; ++jj) {
      float s = 0.f;
#pragma unroll
      for (int j = 0; j < 8; ++j) s = fmaf(qf[j], bflo(p[jj][j]), s);
      s += __shfl_xor(s, 1, 64);   // reduce within the 8-lane head group
      s += __shfl_xor(s, 2, 64);
      s += __shfl_xor(s, 4, 64);
      const float ex = (e + jj < end) ? __expf(s) : 0.f;
      denom += ex;
#pragma unroll
      for (int j = 0; j < 8; ++j) acc[j] = fmaf(ex, bfhi(p[jj][j]), acc[j]);
    }
  }

  const float inv = (end > beg) ? (1.0f / denom) : 0.f;   // deg-0 rows -> 0
  float4 o0 = { acc[0] * inv, acc[1] * inv, acc[2] * inv, acc[3] * inv };
  float4 o1 = { acc[4] * inv, acc[5] * inv, acc[6] * inv, acc[7] * inv };
  float* op = &out[(size_t)node * 512 + lane * 8];
  *(float4*)op = o0;
  *(float4*)(op + 4) = o1;
}

// ---------------------------------------------------------------------------
extern "C" void kernel_launch(void* const* d_in, const int* in_sizes, int n_in,
                              void* d_out, int out_size, void* d_ws, size_t ws_size,
                              hipStream_t stream) {
  const float* h   = (const float*)d_in[0];
  const int*   row = (const int*)d_in[1];
  const int*   col = (const int*)d_in[2];
  const float* Win = (const float*)d_in[3];
  const float* bin = (const float*)d_in[4];
  const float* Wq  = (const float*)d_in[5];
  const float* bq  = (const float*)d_in[6];
  const float* Wk  = (const float*)d_in[7];
  const float* bk  = (const float*)d_in[8];
  const float* Wv  = (const float*)d_in[9];
  const float* bv  = (const float*)d_in[10];
  float* out = (float*)d_out;

  char* ws = (char*)d_ws;
  u16*   qkv     = (u16*)(ws + 0);           // 32768*1536*2 = 100,663,296
  u16*   hb      = (u16*)(ws + 100663296);   // 32768*512*2  =  33,554,432
  u16*   Wt      = (u16*)(ws + 134217728);   // 1536*512*2   =   1,572,864
  float* bias    = (float*)(ws + 135790592); // 1536*4
  int*   deg     = (int*)(ws + 135796736);   // 32768*4
  int*   row_ptr = (int*)(ws + 135927808);   // 32769*4 (+pad)
  int*   cursor  = (int*)(ws + 136058888);   // 32768*4
  int*   dst     = (int*)(ws + 136189960);   // 262144*4
  // transient (aliased into qkv region; consumed by wt_fill BEFORE gemm_qkv
  // writes qkv — same-stream ordering makes this safe):
  u16*   At      = (u16*)(ws + 0);           // 1536*512*2 = 1,572,864
  u16*   Winb    = (u16*)(ws + 1572864);     //  512*512*2 =   524,288

  // 6 dispatches (R5 had 8): bias memset dropped (non-atomic bias zone),
  // fill_csr merged into the gemm_wt launch (independent work, overlapped).
  (void)hipMemsetAsync(deg, 0, NN * sizeof(int), stream);
  hipLaunchKernelGGL(prep_all,
                     dim3(GB_BIAS + GB_TCW + GB_CASTW + GB_CNTD + GB_CASTH),
                     dim3(256), 0, stream,
                     h, hb, Win, Winb, row, deg, Wq, Wk, Wv, At,
                     bin, bq, bk, bv, bias);
  hipLaunchKernelGGL(scan_deg,  dim3(1), dim3(1024), 0, stream, deg, row_ptr, cursor);
  hipLaunchKernelGGL(wt_fill,   dim3(48 + EE / 256), dim3(256), 0, stream,
                     At, Winb, Wt, row, col, cursor, dst);
  hipLaunchKernelGGL(gemm_qkv,  dim3(NQKV / 128, NN / 128), dim3(256), 0, stream, hb, Wt, bias, qkv);
  hipLaunchKernelGGL(attn_agg,  dim3((NN * 64) / 256), dim3(256), 0, stream,
                     qkv, (const u32*)qkv, row_ptr, dst, out);
}

// Round 10
// 335.603 us; speedup vs baseline: 1.0780x; 1.0259x over previous
//
#include <hip/hip_runtime.h>

// Problem constants (fixed by the reference)
#define NN 32768      // nodes
#define EE 262144     // edges
#define DM 512        // input/model dim (K of the big GEMM)
#define NQKV 1536     // q|k|v concatenated
#define NHEAD 8
#define DHEAD 64

typedef unsigned short u16;
typedef unsigned int u32;
typedef __attribute__((ext_vector_type(8))) short bf16x8;   // MFMA A/B operand (8 bf16)
typedef __attribute__((ext_vector_type(4))) float f32x4;    // MFMA C/D
typedef __attribute__((ext_vector_type(8))) u16 u16x8;
typedef __attribute__((ext_vector_type(4))) u32 u32x4;

__device__ __forceinline__ float bf2f(u16 u) {
  union { u32 i; float f; } x; x.i = ((u32)u) << 16; return x.f;
}
__device__ __forceinline__ float bflo(u32 p) {
  union { u32 i; float f; } x; x.i = p << 16; return x.f;
}
__device__ __forceinline__ float bfhi(u32 p) {
  union { u32 i; float f; } x; x.i = p & 0xFFFF0000u; return x.f;
}
__device__ __forceinline__ u16 f2bf(float f) {
  union { float f; u32 i; } x; x.f = f;
  u32 r = x.i + 0x7FFFu + ((x.i >> 16) & 1u);   // RNE
  return (u16)(r >> 16);
}

__device__ __forceinline__ void load_lds16(const u16* g, u16* l) {
  __builtin_amdgcn_global_load_lds(
      (const __attribute__((address_space(1))) char*)(const void*)g,
      (__attribute__((address_space(3))) char*)(void*)l, 16, 0, 0);
}

// XOR chunk swizzle for the 4x16B chunks of a 32-elem LDS row.
__device__ __forceinline__ int swz(int r, int s) {
  return s ^ (r & 3) ^ ((r >> 2) & 1);
}

// ---------------------------------------------------------------------------
// prep_all: all independent preprocessing in ONE launch (R5 verbatim — the
// best-measured build; R8/R9 showed dispatch-count reduction doesn't pay).
// ---------------------------------------------------------------------------
#define GB_CASTH 8192
#define GB_CASTW 128
#define GB_CNTD  1024
#define GB_TCW   192
#define GB_BIAS  96
__global__ void prep_all(const float* __restrict__ h, u16* __restrict__ hb,
                         const float* __restrict__ Win, u16* __restrict__ Winb,
                         const int* __restrict__ row, int* __restrict__ deg,
                         const float* __restrict__ Wq, const float* __restrict__ Wk,
                         const float* __restrict__ Wv, u16* __restrict__ At,
                         const float* __restrict__ bin, const float* __restrict__ bq,
                         const float* __restrict__ bk, const float* __restrict__ bv,
                         float* __restrict__ bias) {
  __shared__ float t[64][65];
  const int tid = threadIdx.x;
  int b = blockIdx.x;

  if (b < GB_CASTH) {                       // ---- cast_h ----
    const int i = (b * 256 + tid) * 8;
    float4 a = *(const float4*)&h[i];
    float4 c = *(const float4*)&h[i + 4];
    u16x8 o = { f2bf(a.x), f2bf(a.y), f2bf(a.z), f2bf(a.w),
                f2bf(c.x), f2bf(c.y), f2bf(c.z), f2bf(c.w) };
    *(u16x8*)&hb[i] = o;
    return;
  }
  b -= GB_CASTH;
  if (b < GB_CASTW) {                       // ---- cast_win ----
    const int i = (b * 256 + tid) * 8;
    float4 a = *(const float4*)&Win[i];
    float4 c = *(const float4*)&Win[i + 4];
    u16x8 o = { f2bf(a.x), f2bf(a.y), f2bf(a.z), f2bf(a.w),
                f2bf(c.x), f2bf(c.y), f2bf(c.z), f2bf(c.w) };
    *(u16x8*)&Winb[i] = o;
    return;
  }
  b -= GB_CASTW;
  if (b < GB_CNTD) {                        // ---- count_deg ----
    const int e = b * 256 + tid;
    atomicAdd(&deg[row[e]], 1);
    return;
  }
  b -= GB_CNTD;
  if (b < GB_TCW) {                         // ---- tcast_w ----
    const int z = b / 64;                   // 0=q,1=k,2=v
    const int r64 = b % 64;
    const float* W = (z == 0) ? Wq : (z == 1) ? Wk : Wv;
    const float scale = (z == 0) ? 0.125f : 1.0f;
    const int m0 = (r64 >> 3) * 64;
    const int j0 = (r64 & 7) * 64;
    const int tx = tid & 63, ty = tid >> 6;
#pragma unroll
    for (int i = 0; i < 16; ++i) {
      const int r = ty * 16 + i;
      t[r][tx] = W[(size_t)(m0 + r) * 512 + (j0 + tx)];   // coalesced over tx
    }
    __syncthreads();
#pragma unroll
    for (int i = 0; i < 16; ++i) {
      const int j = j0 + ty * 16 + i;
      const int pr = (z == 0) ? j : (512 + 2 * j + (z - 1));  // permuted row
      At[(size_t)pr * 512 + (m0 + tx)] = f2bf(t[tx][ty * 16 + i] * scale);
    }
    return;
  }
  b -= GB_TCW;
  {                                         // ---- make_bias partial ----
    const int j = (b % 6) * 256 + tid;      // logical output index 0..1535
    const int m0 = (b / 6) * 32;            // this block's K-slice
    const float* Wsel; const float* bsel; int jj; float scale = 1.0f; int pos;
    if (j < 512)       { Wsel = Wq; bsel = bq; jj = j;        scale = 0.125f; pos = j; }
    else if (j < 1024) { Wsel = Wk; bsel = bk; jj = j - 512;  pos = 512 + 2 * jj; }
    else               { Wsel = Wv; bsel = bv; jj = j - 1024; pos = 513 + 2 * jj; }
    float s0 = 0.f, s1 = 0.f, s2 = 0.f, s3 = 0.f;
#pragma unroll
    for (int m = 0; m < 32; m += 4) {
      s0 = fmaf(bin[m0 + m],     Wsel[(size_t)(m0 + m)     * 512 + jj], s0);
      s1 = fmaf(bin[m0 + m + 1], Wsel[(size_t)(m0 + m + 1) * 512 + jj], s1);
      s2 = fmaf(bin[m0 + m + 2], Wsel[(size_t)(m0 + m + 2) * 512 + jj], s2);
      s3 = fmaf(bin[m0 + m + 3], Wsel[(size_t)(m0 + m + 3) * 512 + jj], s3);
    }
    float add = ((s0 + s1) + (s2 + s3)) * scale;
    if (m0 == 0) add += bsel[jj] * scale;
    atomicAdd(&bias[pos], add);
  }
}

// ---------------------------------------------------------------------------
// CSR build on `row` (scan + fill; counting folded into prep_all)
// ---------------------------------------------------------------------------
__global__ void scan_deg(const int* __restrict__ deg, int* __restrict__ row_ptr,
                         int* __restrict__ cursor) {
  __shared__ int sums[1024];
  const int t = threadIdx.x;
  const int base = t * 32;
  int loc[32];
  int s = 0;
#pragma unroll
  for (int i = 0; i < 32; ++i) { loc[i] = s; s += deg[base + i]; }
  sums[t] = s;
  __syncthreads();
  for (int off = 1; off < 1024; off <<= 1) {
    int v = (t >= off) ? sums[t - off] : 0;
    __syncthreads();
    sums[t] += v;
    __syncthreads();
  }
  const int excl = sums[t] - s;
#pragma unroll
  for (int i = 0; i < 32; ++i) {
    const int val = excl + loc[i];
    row_ptr[base + i] = val;
    cursor[base + i] = val;
  }
  if (t == 1023) row_ptr[NN] = sums[1023];
}

__global__ void fill_csr(const int* __restrict__ row, const int* __restrict__ col,
                         int* __restrict__ cursor, int* __restrict__ dst) {
  const int e = blockIdx.x * 256 + threadIdx.x;
  const int r = row[e];
  const int p = atomicAdd(&cursor[r], 1);
  dst[p] = col[e];
}

// ---------------------------------------------------------------------------
// Compose GEMM: Wt[j][kk] = sum_m At[j][m] * Winb[kk][m]
// M=1536, N=512, K=512. 128^2 + 2-phase pipeline (R5-proven form).
// ---------------------------------------------------------------------------
__global__ __launch_bounds__(256, 2) void gemm_wt(
    const u16* __restrict__ A,    // At [1536][512] bf16 (rows pre-permuted)
    const u16* __restrict__ B,    // Winb [512][512] bf16 (B^T layout)
    u16* __restrict__ C) {        // Wt [1536][512] bf16
  __shared__ u16 As[2][128 * 32];
  __shared__ u16 Bs[2][128 * 32];
  const int tid = threadIdx.x;
  const int lane = tid & 63;
  const int wave = tid >> 6;
  const int quad = lane >> 4;
  const int l16 = lane & 15;
  const int m0 = blockIdx.y * 128;
  const int n0 = blockIdx.x * 128;
  const int wm = (wave >> 1) * 64;
  const int wn = (wave & 1) * 64;

  const int c0 = tid, c1 = tid + 256;
  const int r0 = c0 >> 2, ko0 = swz(r0, c0 & 3) * 8;
  const int r1 = c1 >> 2, ko1 = swz(r1, c1 & 3) * 8;
  const u16* Ag0 = A + (size_t)(m0 + r0) * DM + ko0;
  const u16* Ag1 = A + (size_t)(m0 + r1) * DM + ko1;
  const u16* Bg0 = B + (size_t)(n0 + r0) * DM + ko0;
  const u16* Bg1 = B + (size_t)(n0 + r1) * DM + ko1;

  f32x4 acc[4][4];
#pragma unroll
  for (int i = 0; i < 4; ++i)
#pragma unroll
    for (int j = 0; j < 4; ++j) acc[i][j] = (f32x4){0.f, 0.f, 0.f, 0.f};

  load_lds16(Ag0, &As[0][c0 * 8]);
  load_lds16(Bg0, &Bs[0][c0 * 8]);
  load_lds16(Ag1, &As[0][c1 * 8]);
  load_lds16(Bg1, &Bs[0][c1 * 8]);
  __syncthreads();

  int cur = 0;
#pragma unroll
  for (int kt = 32; kt < DM; kt += 32) {
    load_lds16(Ag0 + kt, &As[cur ^ 1][c0 * 8]);
    load_lds16(Bg0 + kt, &Bs[cur ^ 1][c0 * 8]);
    load_lds16(Ag1 + kt, &As[cur ^ 1][c1 * 8]);
    load_lds16(Bg1 + kt, &Bs[cur ^ 1][c1 * 8]);
    bf16x8 a[4], b[4];
#pragma unroll
    for (int i = 0; i < 4; ++i) {
      const int ra = wm + i * 16 + l16;
      const int rb = wn + i * 16 + l16;
      a[i] = *(const bf16x8*)&As[cur][ra * 32 + swz(ra, quad) * 8];
      b[i] = *(const bf16x8*)&Bs[cur][rb * 32 + swz(rb, quad) * 8];
    }
#pragma unroll
    for (int mi = 0; mi < 4; ++mi)
#pragma unroll
      for (int ni = 0; ni < 4; ++ni)
        acc[mi][ni] = __builtin_amdgcn_mfma_f32_16x16x32_bf16(a[mi], b[ni], acc[mi][ni], 0, 0, 0);
    __syncthreads();
    cur ^= 1;
  }
  {
    bf16x8 a[4], b[4];
#pragma unroll
    for (int i = 0; i < 4; ++i) {
      const int ra = wm + i * 16 + l16;
      const int rb = wn + i * 16 + l16;
      a[i] = *(const bf16x8*)&As[cur][ra * 32 + swz(ra, quad) * 8];
      b[i] = *(const bf16x8*)&Bs[cur][rb * 32 + swz(rb, quad) * 8];
    }
#pragma unroll
    for (int mi = 0; mi < 4; ++mi)
#pragma unroll
      for (int ni = 0; ni < 4; ++ni)
        acc[mi][ni] = __builtin_amdgcn_mfma_f32_16x16x32_bf16(a[mi], b[ni], acc[mi][ni], 0, 0, 0);
  }

#pragma unroll
  for (int ni = 0; ni < 4; ++ni) {
    const int coln = n0 + wn + ni * 16 + l16;
#pragma unroll
    for (int mi = 0; mi < 4; ++mi) {
#pragma unroll
      for (int r = 0; r < 4; ++r) {
        const int rowm = m0 + wm + mi * 16 + quad * 4 + r;
        C[(size_t)rowm * 512 + coln] = f2bf(acc[mi][ni][r]);
      }
    }
  }
}

// ---------------------------------------------------------------------------
// QKV = h_bf16 @ Wt^T + bias   (M=32768, N=1536, K=512)
// WIDENED: 128M x 256N tile, 256 threads / 4 waves (each 64M x 128N), ring-3
// LDS (72 KiB -> 2 blocks/CU) with counted vmcnt(6) + lgkmcnt(0) barriers.
// Rationale: per K-step each wave now issues 32 MFMAs on 12 fragment reads
// (was 16 on 8) -> 2x MFMA per barrier; unlike R2's 512-thread 256^2 attempt
// this keeps 2 blocks/CU so inter-block overlap survives. vmcnt math: at
// barrier t, outstanding = tiles t,t+1 (6 loads each); vmcnt(6) drains
// exactly tile t. Numerics: identical per-element MFMA chains as R5.
// ---------------------------------------------------------------------------
__global__ __launch_bounds__(256, 2) void gemm_qkv(
    const u16* __restrict__ A,    // [32768,512] bf16, row-major
    const u16* __restrict__ B,    // [1536,512] bf16, N-major, rows permuted
    const float* __restrict__ bias,  // permuted to match columns
    u16* __restrict__ C) {        // qkv [32768,1536] bf16 unified
  __shared__ u16 As[3][128 * 32];   // 3 x 8 KiB
  __shared__ u16 Bs[3][256 * 32];   // 3 x 16 KiB
  const int tid = threadIdx.x;
  const int lane = tid & 63;
  const int wave = tid >> 6;
  const int quad = lane >> 4;
  const int l16 = lane & 15;

  // XCD swizzle: 1536 blocks = 8 XCDs x 192 (bijective). Each XCD gets 32
  // consecutive row-panels x all 6 col-tiles -> A panel refetch ~once/XCD.
  const int bid = blockIdx.y * 6 + blockIdx.x;
  const int sw = (bid & 7) * 192 + (bid >> 3);
  const int bx = sw % 6;
  const int by = sw / 6;
  const int m0 = by * 128;
  const int n0 = bx * 256;
  const int wm = (wave >> 1) * 64;    // 0 / 64
  const int wn = (wave & 1) * 128;    // 0 / 128

  // A staging: 512 slots of 16B, 2 per thread
  const int c0 = tid, c1 = tid + 256;
  const int ra0 = c0 >> 2, ko0 = swz(ra0, c0 & 3) * 8;
  const int ra1 = c1 >> 2, ko1 = swz(ra1, c1 & 3) * 8;
  const u16* Ag0 = A + (size_t)(m0 + ra0) * DM + ko0;
  const u16* Ag1 = A + (size_t)(m0 + ra1) * DM + ko1;
  // B staging: 1024 slots of 16B, 4 per thread
  const int s0 = tid,       rb0 = s0 >> 2, kb0 = swz(rb0, s0 & 3) * 8;
  const int s1 = tid + 256, rb1 = s1 >> 2, kb1 = swz(rb1, s1 & 3) * 8;
  const int s2 = tid + 512, rb2 = s2 >> 2, kb2 = swz(rb2, s2 & 3) * 8;
  const int s3 = tid + 768, rb3 = s3 >> 2, kb3 = swz(rb3, s3 & 3) * 8;
  const u16* Bg0 = B + (size_t)(n0 + rb0) * DM + kb0;
  const u16* Bg1 = B + (size_t)(n0 + rb1) * DM + kb1;
  const u16* Bg2 = B + (size_t)(n0 + rb2) * DM + kb2;
  const u16* Bg3 = B + (size_t)(n0 + rb3) * DM + kb3;

  f32x4 acc[4][8];
#pragma unroll
  for (int i = 0; i < 4; ++i)
#pragma unroll
    for (int j = 0; j < 8; ++j) acc[i][j] = (f32x4){0.f, 0.f, 0.f, 0.f};

  // prologue: stage tiles 0,1 (6 loads per tile per thread: A x2, B x4)
#pragma unroll
  for (int t = 0; t < 2; ++t) {
    const int kg = t * 32;
    load_lds16(Ag0 + kg, &As[t][c0 * 8]);
    load_lds16(Ag1 + kg, &As[t][c1 * 8]);
    load_lds16(Bg0 + kg, &Bs[t][s0 * 8]);
    load_lds16(Bg1 + kg, &Bs[t][s1 * 8]);
    load_lds16(Bg2 + kg, &Bs[t][s2 * 8]);
    load_lds16(Bg3 + kg, &Bs[t][s3 * 8]);
  }

#pragma unroll
  for (int t = 0; t < 16; ++t) {
    const int bt = t % 3;
    // counted wait: tile t landed (oldest 6), tile t+1 stays in flight;
    // lgkmcnt(0) = this wave's prior ds_reads done -> overwrite-safe (R4 fix).
    if (t < 15) asm volatile("s_waitcnt vmcnt(6) lgkmcnt(0)\n\ts_barrier" ::: "memory");
    else        asm volatile("s_waitcnt vmcnt(0) lgkmcnt(0)\n\ts_barrier" ::: "memory");
    // stage t+2 into buf[(t+2)%3] = buf[(t-1)%3]; its readers completed
    // before the barrier above (lgkmcnt(0) drained them).
    if (t < 14) {
      const int b2 = (t + 2) % 3;
      const int kg = (t + 2) * 32;
      load_lds16(Ag0 + kg, &As[b2][c0 * 8]);
      load_lds16(Ag1 + kg, &As[b2][c1 * 8]);
      load_lds16(Bg0 + kg, &Bs[b2][s0 * 8]);
      load_lds16(Bg1 + kg, &Bs[b2][s1 * 8]);
      load_lds16(Bg2 + kg, &Bs[b2][s2 * 8]);
      load_lds16(Bg3 + kg, &Bs[b2][s3 * 8]);
    }
    bf16x8 a[4], b[8];
#pragma unroll
    for (int i = 0; i < 4; ++i) {
      const int ra = wm + i * 16 + l16;
      a[i] = *(const bf16x8*)&As[bt][ra * 32 + swz(ra, quad) * 8];
    }
#pragma unroll
    for (int i = 0; i < 8; ++i) {
      const int rb = wn + i * 16 + l16;
      b[i] = *(const bf16x8*)&Bs[bt][rb * 32 + swz(rb, quad) * 8];
    }
#pragma unroll
    for (int mi = 0; mi < 4; ++mi)
#pragma unroll
      for (int ni = 0; ni < 8; ++ni)
        acc[mi][ni] = __builtin_amdgcn_mfma_f32_16x16x32_bf16(a[mi], b[ni], acc[mi][ni], 0, 0, 0);
  }

  // epilogue: C/D layout col=lane&15, row=quad*4+r (verified m89/m91)
#pragma unroll
  for (int ni = 0; ni < 8; ++ni) {
    const int coln = n0 + wn + ni * 16 + l16;
    const float bv = bias[coln];
#pragma unroll
    for (int mi = 0; mi < 4; ++mi) {
#pragma unroll
      for (int r = 0; r < 4; ++r) {
        const int rowm = m0 + wm + mi * 16 + quad * 4 + r;
        C[(size_t)rowm * NQKV + coln] = f2bf(acc[mi][ni][r] + bv);
      }
    }
  }
}

// ---------------------------------------------------------------------------
// Fused sparse attention: ONE WAVE PER NODE; lane l owns dims l*8..l*8+7.
// Round-1 proven form (CHUNK=4 clamped, VGPR 48): fastest of the three
// measured structural variants (87-91 us, FETCH pinned 267 MB -> gather-bound).
// ---------------------------------------------------------------------------
__global__ __launch_bounds__(256) void attn_agg(
    const u16* __restrict__ qkv16, const u32* __restrict__ qkv32,
    const int* __restrict__ row_ptr, const int* __restrict__ dst,
    float* __restrict__ out) {
  const int gt = blockIdx.x * 256 + threadIdx.x;
  const int node = gt >> 6;
  const int lane = gt & 63;
  const u16x8 qr = *(const u16x8*)&qkv16[(size_t)node * NQKV + lane * 8];
  float qf[8];
#pragma unroll
  for (int j = 0; j < 8; ++j) qf[j] = bf2f(qr[j]);

  const int beg = row_ptr[node];
  const int end = row_ptr[node + 1];
  float acc[8] = {0.f,0.f,0.f,0.f,0.f,0.f,0.f,0.f};
  float denom = 0.f;

  for (int e = beg; e < end; e += 4) {
    u32 p[4][8];
    int idx[4];
#pragma unroll
    for (int jj = 0; jj < 4; ++jj) {
      const int ee = min(e + jj, end - 1);
      idx[jj] = dst[ee];
    }
#pragma unroll
    for (int jj = 0; jj < 4; ++jj) {
      const u32* pp = qkv32 + (size_t)idx[jj] * 768 + 256 + lane * 8;
      *(u32x4*)&p[jj][0] = *(const u32x4*)pp;        // dwordx4
      *(u32x4*)&p[jj][4] = *(const u32x4*)(pp + 4);  // dwordx4
    }
#pragma unroll
    for (int jj = 0; jj < 4; ++jj) {
      float s = 0.f;
#pragma unroll
      for (int j = 0; j < 8; ++j) s = fmaf(qf[j], bflo(p[jj][j]), s);
      s += __shfl_xor(s, 1, 64);   // reduce within the 8-lane head group
      s += __shfl_xor(s, 2, 64);
      s += __shfl_xor(s, 4, 64);
      const float ex = (e + jj < end) ? __expf(s) : 0.f;
      denom += ex;
#pragma unroll
      for (int j = 0; j < 8; ++j) acc[j] = fmaf(ex, bfhi(p[jj][j]), acc[j]);
    }
  }

  const float inv = (end > beg) ? (1.0f / denom) : 0.f;   // deg-0 rows -> 0
  float4 o0 = { acc[0] * inv, acc[1] * inv, acc[2] * inv, acc[3] * inv };
  float4 o1 = { acc[4] * inv, acc[5] * inv, acc[6] * inv, acc[7] * inv };
  float* op = &out[(size_t)node * 512 + lane * 8];
  *(float4*)op = o0;
  *(float4*)(op + 4) = o1;
}

// ---------------------------------------------------------------------------
extern "C" void kernel_launch(void* const* d_in, const int* in_sizes, int n_in,
                              void* d_out, int out_size, void* d_ws, size_t ws_size,
                              hipStream_t stream) {
  const float* h   = (const float*)d_in[0];
  const int*   row = (const int*)d_in[1];
  const int*   col = (const int*)d_in[2];
  const float* Win = (const float*)d_in[3];
  const float* bin = (const float*)d_in[4];
  const float* Wq  = (const float*)d_in[5];
  const float* bq  = (const float*)d_in[6];
  const float* Wk  = (const float*)d_in[7];
  const float* bk  = (const float*)d_in[8];
  const float* Wv  = (const float*)d_in[9];
  const float* bv  = (const float*)d_in[10];
  float* out = (float*)d_out;

  char* ws = (char*)d_ws;
  u16*   qkv     = (u16*)(ws + 0);           // 32768*1536*2 = 100,663,296
  u16*   hb      = (u16*)(ws + 100663296);   // 32768*512*2  =  33,554,432
  u16*   Wt      = (u16*)(ws + 134217728);   // 1536*512*2   =   1,572,864
  float* bias    = (float*)(ws + 135790592); // 1536*4
  int*   deg     = (int*)(ws + 135796736);   // 32768*4
  int*   row_ptr = (int*)(ws + 135927808);   // 32769*4 (+pad)
  int*   cursor  = (int*)(ws + 136058888);   // 32768*4
  int*   dst     = (int*)(ws + 136189960);   // 262144*4
  // transient (aliased into qkv region; consumed by gemm_wt BEFORE gemm_qkv
  // writes qkv — same-stream ordering makes this safe):
  u16*   At      = (u16*)(ws + 0);           // 1536*512*2 = 1,572,864
  u16*   Winb    = (u16*)(ws + 1572864);     //  512*512*2 =   524,288

  (void)hipMemsetAsync(deg, 0, NN * sizeof(int), stream);
  (void)hipMemsetAsync(bias, 0, NQKV * sizeof(float), stream);
  hipLaunchKernelGGL(prep_all,
                     dim3(GB_CASTH + GB_CASTW + GB_CNTD + GB_TCW + GB_BIAS),
                     dim3(256), 0, stream,
                     h, hb, Win, Winb, row, deg, Wq, Wk, Wv, At,
                     bin, bq, bk, bv, bias);
  hipLaunchKernelGGL(scan_deg,  dim3(1), dim3(1024), 0, stream, deg, row_ptr, cursor);
  hipLaunchKernelGGL(fill_csr,  dim3(EE / 256), dim3(256), 0, stream, row, col, cursor, dst);
  hipLaunchKernelGGL(gemm_wt,   dim3(512 / 128, 1536 / 128), dim3(256), 0, stream, At, Winb, Wt);
  hipLaunchKernelGGL(gemm_qkv,  dim3(NQKV / 256, NN / 128), dim3(256), 0, stream, hb, Wt, bias, qkv);
  hipLaunchKernelGGL(attn_agg,  dim3((NN * 64) / 256), dim3(256), 0, stream,
                     qkv, (const u32*)qkv, row_ptr, dst, out);
}

// Round 11
// 330.665 us; speedup vs baseline: 1.0941x; 1.0149x over previous
//
#include <hip/hip_runtime.h>

// Problem constants (fixed by the reference)
#define NN 32768      // nodes
#define EE 262144     // edges
#define DM 512        // input/model dim (K of the big GEMM)
#define NQKV 1536     // q|k|v concatenated
#define NHEAD 8
#define DHEAD 64

typedef unsigned short u16;
typedef unsigned int u32;
typedef __attribute__((ext_vector_type(8))) short bf16x8;   // MFMA A/B operand (8 bf16)
typedef __attribute__((ext_vector_type(4))) float f32x4;    // MFMA C/D
typedef __attribute__((ext_vector_type(8))) u16 u16x8;
typedef __attribute__((ext_vector_type(4))) u32 u32x4;

__device__ __forceinline__ float bf2f(u16 u) {
  union { u32 i; float f; } x; x.i = ((u32)u) << 16; return x.f;
}
__device__ __forceinline__ float bflo(u32 p) {
  union { u32 i; float f; } x; x.i = p << 16; return x.f;
}
__device__ __forceinline__ float bfhi(u32 p) {
  union { u32 i; float f; } x; x.i = p & 0xFFFF0000u; return x.f;
}
__device__ __forceinline__ u16 f2bf(float f) {
  union { float f; u32 i; } x; x.f = f;
  u32 r = x.i + 0x7FFFu + ((x.i >> 16) & 1u);   // RNE
  return (u16)(r >> 16);
}

__device__ __forceinline__ void load_lds16(const u16* g, u16* l) {
  __builtin_amdgcn_global_load_lds(
      (const __attribute__((address_space(1))) char*)(const void*)g,
      (__attribute__((address_space(3))) char*)(void*)l, 16, 0, 0);
}

// XOR chunk swizzle for the 4x16B chunks of a 32-elem LDS row.
__device__ __forceinline__ int swz(int r, int s) {
  return s ^ (r & 3) ^ ((r >> 2) & 1);
}

// ---------------------------------------------------------------------------
// prep_all: all independent preprocessing in ONE launch (R5 verbatim).
// ---------------------------------------------------------------------------
#define GB_CASTH 8192
#define GB_CASTW 128
#define GB_CNTD  1024
#define GB_TCW   192
#define GB_BIAS  96
__global__ void prep_all(const float* __restrict__ h, u16* __restrict__ hb,
                         const float* __restrict__ Win, u16* __restrict__ Winb,
                         const int* __restrict__ row, int* __restrict__ deg,
                         const float* __restrict__ Wq, const float* __restrict__ Wk,
                         const float* __restrict__ Wv, u16* __restrict__ At,
                         const float* __restrict__ bin, const float* __restrict__ bq,
                         const float* __restrict__ bk, const float* __restrict__ bv,
                         float* __restrict__ bias) {
  __shared__ float t[64][65];
  const int tid = threadIdx.x;
  int b = blockIdx.x;

  if (b < GB_CASTH) {                       // ---- cast_h ----
    const int i = (b * 256 + tid) * 8;
    float4 a = *(const float4*)&h[i];
    float4 c = *(const float4*)&h[i + 4];
    u16x8 o = { f2bf(a.x), f2bf(a.y), f2bf(a.z), f2bf(a.w),
                f2bf(c.x), f2bf(c.y), f2bf(c.z), f2bf(c.w) };
    *(u16x8*)&hb[i] = o;
    return;
  }
  b -= GB_CASTH;
  if (b < GB_CASTW) {                       // ---- cast_win ----
    const int i = (b * 256 + tid) * 8;
    float4 a = *(const float4*)&Win[i];
    float4 c = *(const float4*)&Win[i + 4];
    u16x8 o = { f2bf(a.x), f2bf(a.y), f2bf(a.z), f2bf(a.w),
                f2bf(c.x), f2bf(c.y), f2bf(c.z), f2bf(c.w) };
    *(u16x8*)&Winb[i] = o;
    return;
  }
  b -= GB_CASTW;
  if (b < GB_CNTD) {                        // ---- count_deg ----
    const int e = b * 256 + tid;
    atomicAdd(&deg[row[e]], 1);
    return;
  }
  b -= GB_CNTD;
  if (b < GB_TCW) {                         // ---- tcast_w ----
    const int z = b / 64;                   // 0=q,1=k,2=v
    const int r64 = b % 64;
    const float* W = (z == 0) ? Wq : (z == 1) ? Wk : Wv;
    const float scale = (z == 0) ? 0.125f : 1.0f;
    const int m0 = (r64 >> 3) * 64;
    const int j0 = (r64 & 7) * 64;
    const int tx = tid & 63, ty = tid >> 6;
#pragma unroll
    for (int i = 0; i < 16; ++i) {
      const int r = ty * 16 + i;
      t[r][tx] = W[(size_t)(m0 + r) * 512 + (j0 + tx)];   // coalesced over tx
    }
    __syncthreads();
#pragma unroll
    for (int i = 0; i < 16; ++i) {
      const int j = j0 + ty * 16 + i;
      const int pr = (z == 0) ? j : (512 + 2 * j + (z - 1));  // permuted row
      At[(size_t)pr * 512 + (m0 + tx)] = f2bf(t[tx][ty * 16 + i] * scale);
    }
    return;
  }
  b -= GB_TCW;
  {                                         // ---- make_bias partial ----
    const int j = (b % 6) * 256 + tid;      // logical output index 0..1535
    const int m0 = (b / 6) * 32;            // this block's K-slice
    const float* Wsel; const float* bsel; int jj; float scale = 1.0f; int pos;
    if (j < 512)       { Wsel = Wq; bsel = bq; jj = j;        scale = 0.125f; pos = j; }
    else if (j < 1024) { Wsel = Wk; bsel = bk; jj = j - 512;  pos = 512 + 2 * jj; }
    else               { Wsel = Wv; bsel = bv; jj = j - 1024; pos = 513 + 2 * jj; }
    float s0 = 0.f, s1 = 0.f, s2 = 0.f, s3 = 0.f;
#pragma unroll
    for (int m = 0; m < 32; m += 4) {
      s0 = fmaf(bin[m0 + m],     Wsel[(size_t)(m0 + m)     * 512 + jj], s0);
      s1 = fmaf(bin[m0 + m + 1], Wsel[(size_t)(m0 + m + 1) * 512 + jj], s1);
      s2 = fmaf(bin[m0 + m + 2], Wsel[(size_t)(m0 + m + 2) * 512 + jj], s2);
      s3 = fmaf(bin[m0 + m + 3], Wsel[(size_t)(m0 + m + 3) * 512 + jj], s3);
    }
    float add = ((s0 + s1) + (s2 + s3)) * scale;
    if (m0 == 0) add += bsel[jj] * scale;
    atomicAdd(&bias[pos], add);
  }
}

// ---------------------------------------------------------------------------
// CSR build on `row` (scan + fill; counting folded into prep_all)
// ---------------------------------------------------------------------------
__global__ void scan_deg(const int* __restrict__ deg, int* __restrict__ row_ptr,
                         int* __restrict__ cursor) {
  __shared__ int sums[1024];
  const int t = threadIdx.x;
  const int base = t * 32;
  int loc[32];
  int s = 0;
#pragma unroll
  for (int i = 0; i < 32; ++i) { loc[i] = s; s += deg[base + i]; }
  sums[t] = s;
  __syncthreads();
  for (int off = 1; off < 1024; off <<= 1) {
    int v = (t >= off) ? sums[t - off] : 0;
    __syncthreads();
    sums[t] += v;
    __syncthreads();
  }
  const int excl = sums[t] - s;
#pragma unroll
  for (int i = 0; i < 32; ++i) {
    const int val = excl + loc[i];
    row_ptr[base + i] = val;
    cursor[base + i] = val;
  }
  if (t == 1023) row_ptr[NN] = sums[1023];
}

__global__ void fill_csr(const int* __restrict__ row, const int* __restrict__ col,
                         int* __restrict__ cursor, int* __restrict__ dst) {
  const int e = blockIdx.x * 256 + threadIdx.x;
  const int r = row[e];
  const int p = atomicAdd(&cursor[r], 1);
  dst[p] = col[e];
}

// ---------------------------------------------------------------------------
// Compose GEMM: Wt[j][kk] = sum_m At[j][m] * Winb[kk][m]
// M=1536, N=512, K=512. 128^2 + 2-phase pipeline (R5-proven form).
// ---------------------------------------------------------------------------
__global__ __launch_bounds__(256, 2) void gemm_wt(
    const u16* __restrict__ A,    // At [1536][512] bf16 (rows pre-permuted)
    const u16* __restrict__ B,    // Winb [512][512] bf16 (B^T layout)
    u16* __restrict__ C) {        // Wt [1536][512] bf16
  __shared__ u16 As[2][128 * 32];
  __shared__ u16 Bs[2][128 * 32];
  const int tid = threadIdx.x;
  const int lane = tid & 63;
  const int wave = tid >> 6;
  const int quad = lane >> 4;
  const int l16 = lane & 15;
  const int m0 = blockIdx.y * 128;
  const int n0 = blockIdx.x * 128;
  const int wm = (wave >> 1) * 64;
  const int wn = (wave & 1) * 64;

  const int c0 = tid, c1 = tid + 256;
  const int r0 = c0 >> 2, ko0 = swz(r0, c0 & 3) * 8;
  const int r1 = c1 >> 2, ko1 = swz(r1, c1 & 3) * 8;
  const u16* Ag0 = A + (size_t)(m0 + r0) * DM + ko0;
  const u16* Ag1 = A + (size_t)(m0 + r1) * DM + ko1;
  const u16* Bg0 = B + (size_t)(n0 + r0) * DM + ko0;
  const u16* Bg1 = B + (size_t)(n0 + r1) * DM + ko1;

  f32x4 acc[4][4];
#pragma unroll
  for (int i = 0; i < 4; ++i)
#pragma unroll
    for (int j = 0; j < 4; ++j) acc[i][j] = (f32x4){0.f, 0.f, 0.f, 0.f};

  load_lds16(Ag0, &As[0][c0 * 8]);
  load_lds16(Bg0, &Bs[0][c0 * 8]);
  load_lds16(Ag1, &As[0][c1 * 8]);
  load_lds16(Bg1, &Bs[0][c1 * 8]);
  __syncthreads();

  int cur = 0;
#pragma unroll
  for (int kt = 32; kt < DM; kt += 32) {
    load_lds16(Ag0 + kt, &As[cur ^ 1][c0 * 8]);
    load_lds16(Bg0 + kt, &Bs[cur ^ 1][c0 * 8]);
    load_lds16(Ag1 + kt, &As[cur ^ 1][c1 * 8]);
    load_lds16(Bg1 + kt, &Bs[cur ^ 1][c1 * 8]);
    bf16x8 a[4], b[4];
#pragma unroll
    for (int i = 0; i < 4; ++i) {
      const int ra = wm + i * 16 + l16;
      const int rb = wn + i * 16 + l16;
      a[i] = *(const bf16x8*)&As[cur][ra * 32 + swz(ra, quad) * 8];
      b[i] = *(const bf16x8*)&Bs[cur][rb * 32 + swz(rb, quad) * 8];
    }
#pragma unroll
    for (int mi = 0; mi < 4; ++mi)
#pragma unroll
      for (int ni = 0; ni < 4; ++ni)
        acc[mi][ni] = __builtin_amdgcn_mfma_f32_16x16x32_bf16(a[mi], b[ni], acc[mi][ni], 0, 0, 0);
    __syncthreads();
    cur ^= 1;
  }
  {
    bf16x8 a[4], b[4];
#pragma unroll
    for (int i = 0; i < 4; ++i) {
      const int ra = wm + i * 16 + l16;
      const int rb = wn + i * 16 + l16;
      a[i] = *(const bf16x8*)&As[cur][ra * 32 + swz(ra, quad) * 8];
      b[i] = *(const bf16x8*)&Bs[cur][rb * 32 + swz(rb, quad) * 8];
    }
#pragma unroll
    for (int mi = 0; mi < 4; ++mi)
#pragma unroll
      for (int ni = 0; ni < 4; ++ni)
        acc[mi][ni] = __builtin_amdgcn_mfma_f32_16x16x32_bf16(a[mi], b[ni], acc[mi][ni], 0, 0, 0);
  }

#pragma unroll
  for (int ni = 0; ni < 4; ++ni) {
    const int coln = n0 + wn + ni * 16 + l16;
#pragma unroll
    for (int mi = 0; mi < 4; ++mi) {
#pragma unroll
      for (int r = 0; r < 4; ++r) {
        const int rowm = m0 + wm + mi * 16 + quad * 4 + r;
        C[(size_t)rowm * 512 + coln] = f2bf(acc[mi][ni][r]);
      }
    }
  }
}

// ---------------------------------------------------------------------------
// QKV = h_bf16 @ Wt^T + bias   (M=32768, N=1536, K=512)
// R10 widened structure (128M x 256N, ring-3, counted vmcnt(6)+lgkmcnt(0))
// + NEW: LDS-coalesced epilogue. The old epilogue issued 128 scalar u16
// stores/thread in 32B segments (measured 1.9x write amplification on the
// 256-wide tile, R2: WRITE 190 MB vs 100 logical). Now: stage the 128x256
// C-tile in the dead 72KB ring LDS, then stream out as 16B lane-contiguous
// stores covering full 64B lines. Same f2bf bits -> identical numerics.
// ---------------------------------------------------------------------------
__global__ __launch_bounds__(256, 2) void gemm_qkv(
    const u16* __restrict__ A,    // [32768,512] bf16, row-major
    const u16* __restrict__ B,    // [1536,512] bf16, N-major, rows permuted
    const float* __restrict__ bias,  // permuted to match columns
    u16* __restrict__ C) {        // qkv [32768,1536] bf16 unified
  __shared__ u16 smem[3 * 128 * 32 + 3 * 256 * 32];   // 72 KiB ring / C-stage
  u16 (*As)[128 * 32] = (u16(*)[128 * 32])smem;
  u16 (*Bs)[256 * 32] = (u16(*)[256 * 32])(smem + 3 * 128 * 32);
  const int tid = threadIdx.x;
  const int lane = tid & 63;
  const int wave = tid >> 6;
  const int quad = lane >> 4;
  const int l16 = lane & 15;

  // XCD swizzle: 1536 blocks = 8 XCDs x 192 (bijective).
  const int bid = blockIdx.y * 6 + blockIdx.x;
  const int sw = (bid & 7) * 192 + (bid >> 3);
  const int bx = sw % 6;
  const int by = sw / 6;
  const int m0 = by * 128;
  const int n0 = bx * 256;
  const int wm = (wave >> 1) * 64;    // 0 / 64
  const int wn = (wave & 1) * 128;    // 0 / 128

  // A staging: 512 slots of 16B, 2 per thread
  const int c0 = tid, c1 = tid + 256;
  const int ra0 = c0 >> 2, ko0 = swz(ra0, c0 & 3) * 8;
  const int ra1 = c1 >> 2, ko1 = swz(ra1, c1 & 3) * 8;
  const u16* Ag0 = A + (size_t)(m0 + ra0) * DM + ko0;
  const u16* Ag1 = A + (size_t)(m0 + ra1) * DM + ko1;
  // B staging: 1024 slots of 16B, 4 per thread
  const int s0 = tid,       rb0 = s0 >> 2, kb0 = swz(rb0, s0 & 3) * 8;
  const int s1 = tid + 256, rb1 = s1 >> 2, kb1 = swz(rb1, s1 & 3) * 8;
  const int s2 = tid + 512, rb2 = s2 >> 2, kb2 = swz(rb2, s2 & 3) * 8;
  const int s3 = tid + 768, rb3 = s3 >> 2, kb3 = swz(rb3, s3 & 3) * 8;
  const u16* Bg0 = B + (size_t)(n0 + rb0) * DM + kb0;
  const u16* Bg1 = B + (size_t)(n0 + rb1) * DM + kb1;
  const u16* Bg2 = B + (size_t)(n0 + rb2) * DM + kb2;
  const u16* Bg3 = B + (size_t)(n0 + rb3) * DM + kb3;

  f32x4 acc[4][8];
#pragma unroll
  for (int i = 0; i < 4; ++i)
#pragma unroll
    for (int j = 0; j < 8; ++j) acc[i][j] = (f32x4){0.f, 0.f, 0.f, 0.f};

  // prologue: stage tiles 0,1 (6 loads per tile per thread: A x2, B x4)
#pragma unroll
  for (int t = 0; t < 2; ++t) {
    const int kg = t * 32;
    load_lds16(Ag0 + kg, &As[t][c0 * 8]);
    load_lds16(Ag1 + kg, &As[t][c1 * 8]);
    load_lds16(Bg0 + kg, &Bs[t][s0 * 8]);
    load_lds16(Bg1 + kg, &Bs[t][s1 * 8]);
    load_lds16(Bg2 + kg, &Bs[t][s2 * 8]);
    load_lds16(Bg3 + kg, &Bs[t][s3 * 8]);
  }

#pragma unroll
  for (int t = 0; t < 16; ++t) {
    const int bt = t % 3;
    // counted wait: tile t landed (oldest 6), tile t+1 stays in flight;
    // lgkmcnt(0) = this wave's prior ds_reads done -> overwrite-safe (R4 fix).
    if (t < 15) asm volatile("s_waitcnt vmcnt(6) lgkmcnt(0)\n\ts_barrier" ::: "memory");
    else        asm volatile("s_waitcnt vmcnt(0) lgkmcnt(0)\n\ts_barrier" ::: "memory");
    // stage t+2 into buf[(t+2)%3] = buf[(t-1)%3]; its readers completed
    // before the barrier above (lgkmcnt(0) drained them).
    if (t < 14) {
      const int b2 = (t + 2) % 3;
      const int kg = (t + 2) * 32;
      load_lds16(Ag0 + kg, &As[b2][c0 * 8]);
      load_lds16(Ag1 + kg, &As[b2][c1 * 8]);
      load_lds16(Bg0 + kg, &Bs[b2][s0 * 8]);
      load_lds16(Bg1 + kg, &Bs[b2][s1 * 8]);
      load_lds16(Bg2 + kg, &Bs[b2][s2 * 8]);
      load_lds16(Bg3 + kg, &Bs[b2][s3 * 8]);
    }
    bf16x8 a[4], b[8];
#pragma unroll
    for (int i = 0; i < 4; ++i) {
      const int ra = wm + i * 16 + l16;
      a[i] = *(const bf16x8*)&As[bt][ra * 32 + swz(ra, quad) * 8];
    }
#pragma unroll
    for (int i = 0; i < 8; ++i) {
      const int rb = wn + i * 16 + l16;
      b[i] = *(const bf16x8*)&Bs[bt][rb * 32 + swz(rb, quad) * 8];
    }
#pragma unroll
    for (int mi = 0; mi < 4; ++mi)
#pragma unroll
      for (int ni = 0; ni < 8; ++ni)
        acc[mi][ni] = __builtin_amdgcn_mfma_f32_16x16x32_bf16(a[mi], b[ni], acc[mi][ni], 0, 0, 0);
  }

  // ---- LDS-coalesced epilogue ----
  // All waves' fragment ds_reads are complete (consumed by the final MFMAs);
  // rendezvous, then reuse the ring as a [128][256] u16 C-stage.
  __syncthreads();
  u16* Cs = smem;
#pragma unroll
  for (int ni = 0; ni < 8; ++ni) {
    const int coll = wn + ni * 16 + l16;        // 0..255
    const float bv = bias[n0 + coll];
#pragma unroll
    for (int mi = 0; mi < 4; ++mi) {
#pragma unroll
      for (int r = 0; r < 4; ++r) {
        const int rowl = wm + mi * 16 + quad * 4 + r;   // 0..127
        Cs[rowl * 256 + coll] = f2bf(acc[mi][ni][r] + bv);
      }
    }
  }
  __syncthreads();
  // stream out: 4096 16B-chunks; consecutive lanes -> consecutive 16B
  // (full 64B lines; 32 chunks per 512B row).
#pragma unroll
  for (int k = 0; k < 16; ++k) {
    const int chunk = k * 256 + tid;
    const int r = chunk >> 5;
    const int c = (chunk & 31) * 8;
    *(u16x8*)&C[(size_t)(m0 + r) * NQKV + n0 + c] = *(const u16x8*)&Cs[r * 256 + c];
  }
}

// ---------------------------------------------------------------------------
// Fused sparse attention: ONE WAVE PER NODE; lane l owns dims l*8..l*8+7.
// Round-1 proven form (CHUNK=4 clamped, VGPR 48): fastest of the measured
// structural variants (87-91 us, FETCH pinned 267 MB -> gather-bound).
// ---------------------------------------------------------------------------
__global__ __launch_bounds__(256) void attn_agg(
    const u16* __restrict__ qkv16, const u32* __restrict__ qkv32,
    const int* __restrict__ row_ptr, const int* __restrict__ dst,
    float* __restrict__ out) {
  const int gt = blockIdx.x * 256 + threadIdx.x;
  const int node = gt >> 6;
  const int lane = gt & 63;
  const u16x8 qr = *(const u16x8*)&qkv16[(size_t)node * NQKV + lane * 8];
  float qf[8];
#pragma unroll
  for (int j = 0; j < 8; ++j) qf[j] = bf2f(qr[j]);

  const int beg = row_ptr[node];
  const int end = row_ptr[node + 1];
  float acc[8] = {0.f,0.f,0.f,0.f,0.f,0.f,0.f,0.f};
  float denom = 0.f;

  for (int e = beg; e < end; e += 4) {
    u32 p[4][8];
    int idx[4];
#pragma unroll
    for (int jj = 0; jj < 4; ++jj) {
      const int ee = min(e + jj, end - 1);
      idx[jj] = dst[ee];
    }
#pragma unroll
    for (int jj = 0; jj < 4; ++jj) {
      const u32* pp = qkv32 + (size_t)idx[jj] * 768 + 256 + lane * 8;
      *(u32x4*)&p[jj][0] = *(const u32x4*)pp;        // dwordx4
      *(u32x4*)&p[jj][4] = *(const u32x4*)(pp + 4);  // dwordx4
    }
#pragma unroll
    for (int jj = 0; jj < 4; ++jj) {
      float s = 0.f;
#pragma unroll
      for (int j = 0; j < 8; ++j) s = fmaf(qf[j], bflo(p[jj][j]), s);
      s += __shfl_xor(s, 1, 64);   // reduce within the 8-lane head group
      s += __shfl_xor(s, 2, 64);
      s += __shfl_xor(s, 4, 64);
      const float ex = (e + jj < end) ? __expf(s) : 0.f;
      denom += ex;
#pragma unroll
      for (int j = 0; j < 8; ++j) acc[j] = fmaf(ex, bfhi(p[jj][j]), acc[j]);
    }
  }

  const float inv = (end > beg) ? (1.0f / denom) : 0.f;   // deg-0 rows -> 0
  float4 o0 = { acc[0] * inv, acc[1] * inv, acc[2] * inv, acc[3] * inv };
  float4 o1 = { acc[4] * inv, acc[5] * inv, acc[6] * inv, acc[7] * inv };
  float* op = &out[(size_t)node * 512 + lane * 8];
  *(float4*)op = o0;
  *(float4*)(op + 4) = o1;
}

// ---------------------------------------------------------------------------
extern "C" void kernel_launch(void* const* d_in, const int* in_sizes, int n_in,
                              void* d_out, int out_size, void* d_ws, size_t ws_size,
                              hipStream_t stream) {
  const float* h   = (const float*)d_in[0];
  const int*   row = (const int*)d_in[1];
  const int*   col = (const int*)d_in[2];
  const float* Win = (const float*)d_in[3];
  const float* bin = (const float*)d_in[4];
  const float* Wq  = (const float*)d_in[5];
  const float* bq  = (const float*)d_in[6];
  const float* Wk  = (const float*)d_in[7];
  const float* bk  = (const float*)d_in[8];
  const float* Wv  = (const float*)d_in[9];
  const float* bv  = (const float*)d_in[10];
  float* out = (float*)d_out;

  char* ws = (char*)d_ws;
  u16*   qkv     = (u16*)(ws + 0);           // 32768*1536*2 = 100,663,296
  u16*   hb      = (u16*)(ws + 100663296);   // 32768*512*2  =  33,554,432
  u16*   Wt      = (u16*)(ws + 134217728);   // 1536*512*2   =   1,572,864
  float* bias    = (float*)(ws + 135790592); // 1536*4
  int*   deg     = (int*)(ws + 135796736);   // 32768*4
  int*   row_ptr = (int*)(ws + 135927808);   // 32769*4 (+pad)
  int*   cursor  = (int*)(ws + 136058888);   // 32768*4
  int*   dst     = (int*)(ws + 136189960);   // 262144*4
  // transient (aliased into qkv region; consumed by gemm_wt BEFORE gemm_qkv
  // writes qkv — same-stream ordering makes this safe):
  u16*   At      = (u16*)(ws + 0);           // 1536*512*2 = 1,572,864
  u16*   Winb    = (u16*)(ws + 1572864);     //  512*512*2 =   524,288

  (void)hipMemsetAsync(deg, 0, NN * sizeof(int), stream);
  (void)hipMemsetAsync(bias, 0, NQKV * sizeof(float), stream);
  hipLaunchKernelGGL(prep_all,
                     dim3(GB_CASTH + GB_CASTW + GB_CNTD + GB_TCW + GB_BIAS),
                     dim3(256), 0, stream,
                     h, hb, Win, Winb, row, deg, Wq, Wk, Wv, At,
                     bin, bq, bk, bv, bias);
  hipLaunchKernelGGL(scan_deg,  dim3(1), dim3(1024), 0, stream, deg, row_ptr, cursor);
  hipLaunchKernelGGL(fill_csr,  dim3(EE / 256), dim3(256), 0, stream, row, col, cursor, dst);
  hipLaunchKernelGGL(gemm_wt,   dim3(512 / 128, 1536 / 128), dim3(256), 0, stream, At, Winb, Wt);
  hipLaunchKernelGGL(gemm_qkv,  dim3(NQKV / 256, NN / 128), dim3(256), 0, stream, hb, Wt, bias, qkv);
  hipLaunchKernelGGL(attn_agg,  dim3((NN * 64) / 256), dim3(256), 0, stream,
                     qkv, (const u32*)qkv, row_ptr, dst, out);
}